// Round 4
// baseline (441.962 us; speedup 1.0000x reference)
//
#include <hip/hip_runtime.h>

// Problem constants (fixed-shape problem)
#define BB 4
#define CC 16
#define KK 16
#define HWP (512 * 512)
#define TILE 512
#define NTILES (HWP / TILE)       // 512 tiles per batch -> 2048 blocks
#define THREADS 256
#define JITERS (TILE / 64)        // 8: each iter, 16 lanes x 4 px (float4)
#define NSLICE 8                  // atomic contention slices
#define WSTOT (64 + 1024 + 1024)  // floats per slice: cnt | sum | sq
#define WS_OFF 16                 // floats reserved at ws[0] for done-counter

typedef float f2 __attribute__((ext_vector_type(2)));

__device__ __forceinline__ float fmaxf_(float a, float b) { return a > b ? a : b; }

__device__ __forceinline__ f2 fma2(float m, f2 ee, f2 acc) {
#if __has_builtin(__builtin_elementwise_fma)
    f2 mm = {m, m};
    return __builtin_elementwise_fma(mm, ee, acc);   // -> v_pk_fma_f32
#else
    acc.x = fmaf(m, ee.x, acc.x);
    acc.y = fmaf(m, ee.y, acc.y);
    return acc;
#endif
}

// One fused kernel: masked partial reductions + (last block) loss epilogue.
__global__ __launch_bounds__(THREADS, 4) void disc_fused_kernel(
    const float* __restrict__ emb, const int* __restrict__ masks,
    float* __restrict__ ws, float* __restrict__ out)
{
    __shared__ unsigned short bits[TILE];   // per-pixel 16-bit mask field
    __shared__ int wcnt[4][KK];             // per-wave per-k fg counts
    __shared__ int is_last;
    // finalize-only LDS (fits comfortably alongside; ~14 KB total)
    __shared__ float red[WSTOT];
    __shared__ float means[BB][KK][CC];
    __shared__ float partial[BB];

    const int tid = threadIdx.x;
    const int b = blockIdx.x / NTILES;
    const int tile = blockIdx.x % NTILES;
    const size_t tile0 = (size_t)tile * TILE;
    int* counter = (int*)ws;
    float* slice = ws + WS_OFF + (size_t)(blockIdx.x & (NSLICE - 1)) * WSTOT;

    // ---- phase 1: pack 16 mask planes into per-pixel bitmask in LDS ----
    // thread t owns pixels 2t, 2t+1 (int2 loads, 8B/lane, coalesced per plane)
    const int2* mbase2 = (const int2*)(masks + (size_t)b * KK * HWP + tile0);
    unsigned v0 = 0, v1 = 0;
    #pragma unroll
    for (int k = 0; k < KK; ++k) {
        int2 mm = mbase2[(size_t)k * (HWP / 2) + tid];
        v0 |= (mm.x > 0 ? 1u : 0u) << k;
        v1 |= (mm.y > 0 ? 1u : 0u) << k;
    }
    ((unsigned*)bits)[tid] = v0 | (v1 << 16);   // bits[2t]=v0, bits[2t+1]=v1

    // exact fg counts via ballot (keeps count-FMAs out of the hot loop)
    const int lane = tid & 63;
    const int wave = tid >> 6;
    int mycnt = 0;
    #pragma unroll
    for (int k = 0; k < KK; ++k) {
        unsigned long long b0 = __ballot((v0 >> k) & 1u);
        unsigned long long b1 = __ballot((v1 >> k) & 1u);
        if (lane == k) mycnt = __popcll(b0) + __popcll(b1);
    }
    if (lane < KK) wcnt[wave][lane] = mycnt;
    __syncthreads();

    // ---- phase 2: 16-thread group per channel; 4 px/lane/iter (float4) ----
    const int c = tid >> 4;
    const int l = tid & 15;
    const float4* e4 = (const float4*)(emb + ((size_t)b * CC + c) * HWP + tile0);
    const ushort4* b4 = (const ushort4*)bits;

    f2 acc[KK];   // (sum, sq) per k -> v_pk_fma_f32
    #pragma unroll
    for (int k = 0; k < KK; ++k) { acc[k].x = 0.f; acc[k].y = 0.f; }

    #pragma unroll 4
    for (int j = 0; j < JITERS; ++j) {
        float4 e = e4[j * 16 + l];
        ushort4 vv = b4[j * 16 + l];
        const float ex[4] = {e.x, e.y, e.z, e.w};
        const unsigned vx[4] = {vv.x, vv.y, vv.z, vv.w};
        #pragma unroll
        for (int p = 0; p < 4; ++p) {
            float ev = ex[p];
            f2 ee = {ev, ev * ev};
            unsigned v = vx[p];
            #pragma unroll
            for (int k = 0; k < KK; ++k) {
                float fm = (float)((v >> k) & 1u);
                acc[k] = fma2(fm, ee, acc[k]);
            }
        }
    }

    // ---- butterfly reduce across the 16-lane group; lane l keeps k==l ----
    float out_s = 0.f, out_q = 0.f;
    #pragma unroll
    for (int k = 0; k < KK; ++k) {
        float ts = acc[k].x, tq = acc[k].y;
        #pragma unroll
        for (int d = 8; d >= 1; d >>= 1) {
            ts += __shfl_xor(ts, d, 64);
            tq += __shfl_xor(tq, d, 64);
        }
        if (l == k) { out_s = ts; out_q = tq; }
    }
    atomicAdd(&slice[64 + ((size_t)b * KK + l) * CC + c], out_s);
    atomicAdd(&slice[64 + 1024 + ((size_t)b * KK + l) * CC + c], out_q);
    if (tid < KK) {
        float ctot = (float)(wcnt[0][tid] + wcnt[1][tid] + wcnt[2][tid] + wcnt[3][tid]);
        atomicAdd(&slice[b * KK + tid], ctot);
    }

    // ---- last-block-done: exactly one block runs the epilogue ----
    __threadfence();                       // release our atomics device-wide
    if (tid == 0) {
        int d = atomicAdd(counter, 1);
        is_last = (d == (int)gridDim.x - 1);
    }
    __syncthreads();
    if (!is_last) return;
    __threadfence();                       // acquire before reading ws

    // pre-reduce the NSLICE atomic slices; agent-scope loads for cross-XCD safety
    const float* wsf = ws + WS_OFF;
    for (int idx = tid; idx < WSTOT; idx += THREADS) {
        float t = 0.f;
        #pragma unroll
        for (int s = 0; s < NSLICE; ++s)
            t += __hip_atomic_load(&wsf[(size_t)s * WSTOT + idx],
                                   __ATOMIC_RELAXED, __HIP_MEMORY_SCOPE_AGENT);
        red[idx] = t;
    }
    __syncthreads();

    const float* red_cnt = red;
    const float* red_sum = red + 64;
    const float* red_sq  = red + 64 + 1024;

    const int fb = tid >> 6;      // one wave per batch
    const int flane = tid & 63;

    const float DELTA_PULL = 0.5f;
    const float DELTA_PUSH = 1.5f;
    const float EPS = 1e-6f;

    float cntk = 0.f;
    bool valid = false;
    float pull_k = 0.f;
    if (flane < KK) {
        int k = flane;
        cntk = red_cnt[fb * KK + k];
        valid = cntk > 0.f;
        float safe = fmaxf_(cntk, 1.f);
        float acc_sq = 0.f, acc_ss = 0.f;
        #pragma unroll
        for (int cc = 0; cc < CC; ++cc) {
            float sv = red_sum[(fb * KK + k) * CC + cc];
            means[fb][k][cc] = sv / safe;
            acc_sq += red_sq[(fb * KK + k) * CC + cc];
            acc_ss += sv * sv;
        }
        if (valid) pull_k = (acc_sq - acc_ss / cntk) / (cntk + EPS);
    }

    unsigned long long bal = __ballot(flane < KK && valid);
    float M = (float)__popcll(bal);

    float ps = pull_k;
    #pragma unroll
    for (int d = 32; d >= 1; d >>= 1) ps += __shfl_xor(ps, d, 64);
    float pull_b = ps / fmaxf_(M, 1.f);

    __syncthreads();

    float push = 0.f;
    for (int t = flane; t < KK * KK; t += 64) {
        int i = t >> 4, j = t & 15;
        if (i < j && ((bal >> i) & 1ull) && ((bal >> j) & 1ull)) {
            float d2 = 1e-12f;
            #pragma unroll
            for (int cc = 0; cc < CC; ++cc) {
                float df = means[fb][i][cc] - means[fb][j][cc];
                d2 = fmaf(df, df, d2);
            }
            float dist = sqrtf(d2);
            float h = fmaxf_(DELTA_PUSH - dist, 0.f);
            push += h * h;
        }
    }
    #pragma unroll
    for (int d = 32; d >= 1; d >>= 1) push += __shfl_xor(push, d, 64);

    if (flane == 0) {
        float npairs = M * (M - 1.f) * 0.5f;
        float push_b = (M > 1.f) ? push / fmaxf_(npairs, 1.f) : 0.f;
        partial[fb] = DELTA_PULL * pull_b + push_b;
    }
    __syncthreads();
    if (tid == 0) {
        out[0] = (partial[0] + partial[1] + partial[2] + partial[3]) * 0.25f;
    }
}

extern "C" void kernel_launch(void* const* d_in, const int* in_sizes, int n_in,
                              void* d_out, int out_size, void* d_ws, size_t ws_size,
                              hipStream_t stream) {
    const float* emb = (const float*)d_in[0];
    const int* masks = (const int*)d_in[1];
    float* ws = (float*)d_ws;

    hipMemsetAsync(d_ws, 0, (WS_OFF + NSLICE * WSTOT) * sizeof(float), stream);

    dim3 grid(BB * NTILES);
    disc_fused_kernel<<<grid, THREADS, 0, stream>>>(emb, masks, ws, (float*)d_out);
}

// Round 5
// 181.043 us; speedup vs baseline: 2.4412x; 2.4412x over previous
//
#include <hip/hip_runtime.h>

// Problem constants (fixed-shape problem)
#define BB 4
#define CC 16
#define KK 16
#define HWP (512 * 512)
#define TILE 512
#define NTILES (HWP / TILE)       // 512 tiles per batch -> 2048 blocks
#define THREADS 256
#define JITERS (TILE / 64)        // 8: each iter, 16 lanes x 4 px (float4)
#define NSLICE 16                 // atomic contention slices
#define WSTOT (64 + 1024 + 1024)  // floats per slice: cnt | sum | sq

typedef float f2 __attribute__((ext_vector_type(2)));

__device__ __forceinline__ float fmaxf_(float a, float b) { return a > b ? a : b; }

__device__ __forceinline__ f2 fma2(float m, f2 ee, f2 acc) {
#if __has_builtin(__builtin_elementwise_fma)
    f2 mm = {m, m};
    return __builtin_elementwise_fma(mm, ee, acc);   // -> v_pk_fma_f32
#else
    acc.x = fmaf(m, ee.x, acc.x);
    acc.y = fmaf(m, ee.y, acc.y);
    return acc;
#endif
}

// occupancy note: f2 acc[16] = 32 VGPRs; total need ~50-56. Cap at 64
// (8 waves/EU) so the 2048-block grid can fill all 32 waves/CU.
__global__ __launch_bounds__(THREADS, 8) void disc_partial_kernel(
    const float* __restrict__ emb, const int* __restrict__ masks,
    float* __restrict__ ws)   // NSLICE slices of [cnt 64 | sum 1024 | sq 1024]
{
    __shared__ unsigned short bits[TILE];   // per-pixel 16-bit mask field
    __shared__ int wcnt[4][KK];             // per-wave per-k fg counts

    const int tid = threadIdx.x;
    const int b = blockIdx.x / NTILES;
    const int tile = blockIdx.x % NTILES;
    const size_t tile0 = (size_t)tile * TILE;
    float* slice = ws + (size_t)(blockIdx.x & (NSLICE - 1)) * WSTOT;

    // ---- phase 1: pack 16 mask planes into per-pixel bitmask in LDS ----
    // thread t owns pixels 2t, 2t+1 (int2 loads, 8B/lane, coalesced per plane)
    const int2* mbase2 = (const int2*)(masks + (size_t)b * KK * HWP + tile0);
    unsigned v0 = 0, v1 = 0;
    #pragma unroll
    for (int k = 0; k < KK; ++k) {
        int2 mm = mbase2[(size_t)k * (HWP / 2) + tid];
        v0 |= (mm.x > 0 ? 1u : 0u) << k;
        v1 |= (mm.y > 0 ? 1u : 0u) << k;
    }
    ((unsigned*)bits)[tid] = v0 | (v1 << 16);   // bits[2t]=v0, bits[2t+1]=v1

    // exact fg counts via ballot (keeps count-FMAs out of the hot loop)
    const int lane = tid & 63;
    const int wave = tid >> 6;
    int mycnt = 0;
    #pragma unroll
    for (int k = 0; k < KK; ++k) {
        unsigned long long b0 = __ballot((v0 >> k) & 1u);
        unsigned long long b1 = __ballot((v1 >> k) & 1u);
        if (lane == k) mycnt = __popcll(b0) + __popcll(b1);
    }
    if (lane < KK) wcnt[wave][lane] = mycnt;
    __syncthreads();

    // ---- phase 2: 16-thread group per channel; 4 px/lane/iter (float4) ----
    const int c = tid >> 4;
    const int l = tid & 15;
    const float4* e4 = (const float4*)(emb + ((size_t)b * CC + c) * HWP + tile0);
    const ushort4* b4 = (const ushort4*)bits;

    f2 acc[KK];   // (sum, sq) per k -> v_pk_fma_f32
    #pragma unroll
    for (int k = 0; k < KK; ++k) { acc[k].x = 0.f; acc[k].y = 0.f; }

    #pragma unroll 4
    for (int j = 0; j < JITERS; ++j) {
        float4 e = e4[j * 16 + l];
        ushort4 vv = b4[j * 16 + l];
        const float ex[4] = {e.x, e.y, e.z, e.w};
        const unsigned vx[4] = {vv.x, vv.y, vv.z, vv.w};
        #pragma unroll
        for (int p = 0; p < 4; ++p) {
            float ev = ex[p];
            f2 ee = {ev, ev * ev};
            unsigned v = vx[p];
            #pragma unroll
            for (int k = 0; k < KK; ++k) {
                float fm = (float)((v >> k) & 1u);
                acc[k] = fma2(fm, ee, acc[k]);
            }
        }
    }

    // ---- butterfly reduce across the 16-lane group; lane l keeps k==l ----
    float out_s = 0.f, out_q = 0.f;
    #pragma unroll
    for (int k = 0; k < KK; ++k) {
        float ts = acc[k].x, tq = acc[k].y;
        #pragma unroll
        for (int d = 8; d >= 1; d >>= 1) {
            ts += __shfl_xor(ts, d, 64);
            tq += __shfl_xor(tq, d, 64);
        }
        if (l == k) { out_s = ts; out_q = tq; }
    }
    atomicAdd(&slice[64 + ((size_t)b * KK + l) * CC + c], out_s);
    atomicAdd(&slice[64 + 1024 + ((size_t)b * KK + l) * CC + c], out_q);
    if (tid < KK) {
        float ctot = (float)(wcnt[0][tid] + wcnt[1][tid] + wcnt[2][tid] + wcnt[3][tid]);
        atomicAdd(&slice[b * KK + tid], ctot);
    }
}

__global__ __launch_bounds__(256) void disc_finalize_kernel(
    const float* __restrict__ ws, float* __restrict__ out)
{
    __shared__ float red[WSTOT];             // slice-reduced [cnt|sum|sq]
    __shared__ float means[BB][KK][CC];
    __shared__ float partial[BB];
    const int tid = threadIdx.x;

    // ---- pre-reduce the NSLICE atomic slices with all 256 threads ----
    for (int idx = tid; idx < WSTOT; idx += 256) {
        float t = 0.f;
        #pragma unroll
        for (int s = 0; s < NSLICE; ++s) t += ws[(size_t)s * WSTOT + idx];
        red[idx] = t;
    }
    __syncthreads();

    const float* red_cnt = red;
    const float* red_sum = red + 64;
    const float* red_sq  = red + 64 + 1024;

    const int b = tid >> 6;       // one wave per batch
    const int lane = tid & 63;

    const float DELTA_PULL = 0.5f;
    const float DELTA_PUSH = 1.5f;
    const float EPS = 1e-6f;

    float cntk = 0.f;
    bool valid = false;
    float pull_k = 0.f;
    if (lane < KK) {
        int k = lane;
        cntk = red_cnt[b * KK + k];
        valid = cntk > 0.f;
        float safe = fmaxf_(cntk, 1.f);
        float acc_sq = 0.f, acc_ss = 0.f;
        #pragma unroll
        for (int c = 0; c < CC; ++c) {
            float sv = red_sum[(b * KK + k) * CC + c];
            means[b][k][c] = sv / safe;
            acc_sq += red_sq[(b * KK + k) * CC + c];
            acc_ss += sv * sv;
        }
        if (valid) pull_k = (acc_sq - acc_ss / cntk) / (cntk + EPS);
    }

    unsigned long long bal = __ballot(lane < KK && valid);
    float M = (float)__popcll(bal);

    float ps = pull_k;
    #pragma unroll
    for (int d = 32; d >= 1; d >>= 1) ps += __shfl_xor(ps, d, 64);
    float pull_b = ps / fmaxf_(M, 1.f);

    __syncthreads();

    float push = 0.f;
    for (int t = lane; t < KK * KK; t += 64) {
        int i = t >> 4, j = t & 15;
        if (i < j && ((bal >> i) & 1ull) && ((bal >> j) & 1ull)) {
            float d2 = 1e-12f;
            #pragma unroll
            for (int c = 0; c < CC; ++c) {
                float df = means[b][i][c] - means[b][j][c];
                d2 = fmaf(df, df, d2);
            }
            float dist = sqrtf(d2);
            float h = fmaxf_(DELTA_PUSH - dist, 0.f);
            push += h * h;
        }
    }
    #pragma unroll
    for (int d = 32; d >= 1; d >>= 1) push += __shfl_xor(push, d, 64);

    if (lane == 0) {
        float npairs = M * (M - 1.f) * 0.5f;
        float push_b = (M > 1.f) ? push / fmaxf_(npairs, 1.f) : 0.f;
        partial[b] = DELTA_PULL * pull_b + push_b;
    }
    __syncthreads();
    if (tid == 0) {
        out[0] = (partial[0] + partial[1] + partial[2] + partial[3]) * 0.25f;
    }
}

extern "C" void kernel_launch(void* const* d_in, const int* in_sizes, int n_in,
                              void* d_out, int out_size, void* d_ws, size_t ws_size,
                              hipStream_t stream) {
    const float* emb = (const float*)d_in[0];
    const int* masks = (const int*)d_in[1];
    float* ws = (float*)d_ws;

    hipMemsetAsync(d_ws, 0, NSLICE * WSTOT * sizeof(float), stream);

    dim3 grid(BB * NTILES);
    disc_partial_kernel<<<grid, THREADS, 0, stream>>>(emb, masks, ws);
    disc_finalize_kernel<<<1, 256, 0, stream>>>(ws, (float*)d_out);
}

// Round 6
// 157.992 us; speedup vs baseline: 2.7974x; 1.1459x over previous
//
#include <hip/hip_runtime.h>

// Problem constants (fixed-shape problem)
#define BB 4
#define CC 16
#define KK 16
#define HWP (512 * 512)
#define TP 512                    // pixels per block-tile
#define NTILES (HWP / TP)         // 512 tiles per batch -> 2048 blocks
#define THREADS 256
#define NSLICE 8                  // atomic contention slices
#define WSTOT (64 + 1024 + 1024)  // floats per slice: cnt | sum | sq

typedef short bf16x8 __attribute__((ext_vector_type(8)));   // 8 bf16 (4 VGPRs)
typedef float f32x4 __attribute__((ext_vector_type(4)));    // MFMA C/D

__device__ __forceinline__ float fmaxf_(float a, float b) { return a > b ? a : b; }

// fp32 -> bf16 round-to-nearest-even (bit trick; no NaN in this data)
__device__ __forceinline__ unsigned short f2bf(float f) {
    unsigned u = __float_as_uint(f);
    u += 0x7FFFu + ((u >> 16) & 1u);
    return (unsigned short)(u >> 16);
}

// MFMA formulation: D[k_mask][c_chan] += A[k_mask][p] * B[p][c_chan] over 32-px groups.
// acc = 2 x f32x4 (8 regs) instead of 32 scalar accumulators -> no spill pressure.
__global__ __launch_bounds__(THREADS) void disc_mfma_kernel(
    const float* __restrict__ emb, const int* __restrict__ masks,
    float* __restrict__ ws)   // NSLICE slices of [cnt 64 | sum 1024 | sq 1024]
{
    __shared__ __align__(16) unsigned short bits[TP];  // per-pixel 16-bit mask field
    __shared__ int wcnt[4][KK];                        // per-wave per-k fg counts
    __shared__ float redbuf[4][64][8];                 // cross-wave C-frag reduce (8 KB)

    const int tid = threadIdx.x;
    const int b = blockIdx.x / NTILES;
    const int tile = blockIdx.x % NTILES;
    const size_t tile0 = (size_t)tile * TP;
    float* slice = ws + (size_t)(blockIdx.x & (NSLICE - 1)) * WSTOT;

    // ---- phase 1: pack 16 mask planes into per-pixel bitmask in LDS ----
    // thread t owns pixels 2t, 2t+1 (int2 loads, coalesced per plane)
    const int2* mbase2 = (const int2*)(masks + (size_t)b * KK * HWP + tile0);
    unsigned v0 = 0, v1 = 0;
    #pragma unroll
    for (int k = 0; k < KK; ++k) {
        int2 mm = mbase2[(size_t)k * (HWP / 2) + tid];
        v0 |= (mm.x > 0 ? 1u : 0u) << k;
        v1 |= (mm.y > 0 ? 1u : 0u) << k;
    }
    ((unsigned*)bits)[tid] = v0 | (v1 << 16);   // bits[2t]=v0, bits[2t+1]=v1

    // exact fg counts via ballot (independent of the bf16 MFMA path)
    const int lane = tid & 63;
    const int wave = tid >> 6;
    int mycnt = 0;
    #pragma unroll
    for (int k = 0; k < KK; ++k) {
        unsigned long long b0 = __ballot((v0 >> k) & 1u);
        unsigned long long b1 = __ballot((v1 >> k) & 1u);
        if (lane == k) mycnt = __popcll(b0) + __popcll(b1);
    }
    if (lane < KK) wcnt[wave][lane] = mycnt;
    __syncthreads();

    // ---- phase 2: MFMA over 32-pixel groups; each wave owns 128 px ----
    const int quad = lane >> 4;      // 0..3
    const int r = lane & 15;         // A-row (mask idx) and B-col (channel idx)
    const float* ebase = emb + ((size_t)b * CC + r) * HWP + tile0;  // channel r

    f32x4 acc_s = {0.f, 0.f, 0.f, 0.f};
    f32x4 acc_q = {0.f, 0.f, 0.f, 0.f};

    #pragma unroll
    for (int g = 0; g < 4; ++g) {
        const int p0 = wave * 128 + g * 32;

        // A-frag: mask bit r of pixels p0+quad*8 .. +7 (broadcast LDS read)
        uint4 bw = *(const uint4*)&bits[p0 + quad * 8];
        union { bf16x8 v; unsigned u[4]; } A;
        A.u[0] = ((bw.x >> r) & 0x00010001u) * 0x3F80u;   // 2 px -> packed bf16 {0,1}
        A.u[1] = ((bw.y >> r) & 0x00010001u) * 0x3F80u;
        A.u[2] = ((bw.z >> r) & 0x00010001u) * 0x3F80u;
        A.u[3] = ((bw.w >> r) & 0x00010001u) * 0x3F80u;

        // B-frags: channel r, pixels p0+quad*8 .. +7 (two float4 loads; the
        // wave consumes each channel's 128B window exactly once)
        const float4* ep = (const float4*)(ebase + p0 + quad * 8);
        float4 f0 = ep[0], f1 = ep[1];
        const float e[8] = {f0.x, f0.y, f0.z, f0.w, f1.x, f1.y, f1.z, f1.w};
        union { bf16x8 v; unsigned short s[8]; } Bf, B2;
        #pragma unroll
        for (int i = 0; i < 8; ++i) {
            Bf.s[i] = f2bf(e[i]);
            B2.s[i] = f2bf(e[i] * e[i]);
        }

        acc_s = __builtin_amdgcn_mfma_f32_16x16x32_bf16(A.v, Bf.v, acc_s, 0, 0, 0);
        acc_q = __builtin_amdgcn_mfma_f32_16x16x32_bf16(A.v, B2.v, acc_q, 0, 0, 0);
    }

    // ---- cross-wave C-fragment reduction in LDS, then atomics ----
    #pragma unroll
    for (int j = 0; j < 4; ++j) {
        redbuf[wave][lane][j] = acc_s[j];
        redbuf[wave][lane][4 + j] = acc_q[j];
    }
    __syncthreads();

    for (int fi = tid; fi < 512; fi += THREADS) {
        const int l2 = fi >> 3, j = fi & 7;
        float v = redbuf[0][l2][j] + redbuf[1][l2][j] + redbuf[2][l2][j] + redbuf[3][l2][j];
        const int reg = j & 3, isq = j >> 2;
        const int krow = (l2 >> 4) * 4 + reg;   // C/D: row=(lane>>4)*4+reg
        const int ccol = l2 & 15;               // C/D: col=lane&15
        atomicAdd(&slice[64 + isq * 1024 + ((size_t)b * KK + krow) * CC + ccol], v);
    }
    if (tid < KK) {
        float ctot = (float)(wcnt[0][tid] + wcnt[1][tid] + wcnt[2][tid] + wcnt[3][tid]);
        atomicAdd(&slice[b * KK + tid], ctot);
    }
}

__global__ __launch_bounds__(256) void disc_finalize_kernel(
    const float* __restrict__ ws, float* __restrict__ out)
{
    __shared__ float red[WSTOT];             // slice-reduced [cnt|sum|sq]
    __shared__ float means[BB][KK][CC];
    __shared__ float partial[BB];
    const int tid = threadIdx.x;

    for (int idx = tid; idx < WSTOT; idx += 256) {
        float t = 0.f;
        #pragma unroll
        for (int s = 0; s < NSLICE; ++s) t += ws[(size_t)s * WSTOT + idx];
        red[idx] = t;
    }
    __syncthreads();

    const float* red_cnt = red;
    const float* red_sum = red + 64;
    const float* red_sq  = red + 64 + 1024;

    const int b = tid >> 6;       // one wave per batch
    const int lane = tid & 63;

    const float DELTA_PULL = 0.5f;
    const float DELTA_PUSH = 1.5f;
    const float EPS = 1e-6f;

    float cntk = 0.f;
    bool valid = false;
    float pull_k = 0.f;
    if (lane < KK) {
        int k = lane;
        cntk = red_cnt[b * KK + k];
        valid = cntk > 0.f;
        float safe = fmaxf_(cntk, 1.f);
        float acc_sq = 0.f, acc_ss = 0.f;
        #pragma unroll
        for (int c = 0; c < CC; ++c) {
            float sv = red_sum[(b * KK + k) * CC + c];
            means[b][k][c] = sv / safe;
            acc_sq += red_sq[(b * KK + k) * CC + c];
            acc_ss += sv * sv;
        }
        if (valid) pull_k = (acc_sq - acc_ss / cntk) / (cntk + EPS);
    }

    unsigned long long bal = __ballot(lane < KK && valid);
    float M = (float)__popcll(bal);

    float ps = pull_k;
    #pragma unroll
    for (int d = 32; d >= 1; d >>= 1) ps += __shfl_xor(ps, d, 64);
    float pull_b = ps / fmaxf_(M, 1.f);

    __syncthreads();

    float push = 0.f;
    for (int t = lane; t < KK * KK; t += 64) {
        int i = t >> 4, j = t & 15;
        if (i < j && ((bal >> i) & 1ull) && ((bal >> j) & 1ull)) {
            float d2 = 1e-12f;
            #pragma unroll
            for (int c = 0; c < CC; ++c) {
                float df = means[b][i][c] - means[b][j][c];
                d2 = fmaf(df, df, d2);
            }
            float dist = sqrtf(d2);
            float h = fmaxf_(DELTA_PUSH - dist, 0.f);
            push += h * h;
        }
    }
    #pragma unroll
    for (int d = 32; d >= 1; d >>= 1) push += __shfl_xor(push, d, 64);

    if (lane == 0) {
        float npairs = M * (M - 1.f) * 0.5f;
        float push_b = (M > 1.f) ? push / fmaxf_(npairs, 1.f) : 0.f;
        partial[b] = DELTA_PULL * pull_b + push_b;
    }
    __syncthreads();
    if (tid == 0) {
        out[0] = (partial[0] + partial[1] + partial[2] + partial[3]) * 0.25f;
    }
}

extern "C" void kernel_launch(void* const* d_in, const int* in_sizes, int n_in,
                              void* d_out, int out_size, void* d_ws, size_t ws_size,
                              hipStream_t stream) {
    const float* emb = (const float*)d_in[0];
    const int* masks = (const int*)d_in[1];
    float* ws = (float*)d_ws;

    hipMemsetAsync(d_ws, 0, NSLICE * WSTOT * sizeof(float), stream);

    dim3 grid(BB * NTILES);
    disc_mfma_kernel<<<grid, THREADS, 0, stream>>>(emb, masks, ws);
    disc_finalize_kernel<<<1, 256, 0, stream>>>(ws, (float*)d_out);
}

// Round 7
// 157.223 us; speedup vs baseline: 2.8111x; 1.0049x over previous
//
#include <hip/hip_runtime.h>

// Problem constants (fixed-shape problem)
#define BB 4
#define CC 16
#define KK 16
#define HWP (512 * 512)
#define TPB 1024                  // pixels per block (4 waves x 256)
#define TPW 256                   // pixels per wave
#define NTILES (HWP / TPB)        // 256 tiles per batch -> 1024 blocks
#define THREADS 256
#define NSLICE 16                 // atomic contention slices
#define WSTOT (64 + 1024 + 1024)  // floats per slice: cnt | sum | sq

typedef short bf16x8 __attribute__((ext_vector_type(8)));   // 8 bf16 (4 VGPRs)
typedef float f32x4 __attribute__((ext_vector_type(4)));    // MFMA C/D

__device__ __forceinline__ float fmaxf_(float a, float b) { return a > b ? a : b; }

// fp32 -> bf16 round-to-nearest-even (bit trick; no NaN in this data)
__device__ __forceinline__ unsigned short f2bf(float f) {
    unsigned u = __float_as_uint(f);
    u += 0x7FFFu + ((u >> 16) & 1u);
    return (unsigned short)(u >> 16);
}

// Barrier-free MFMA kernel: each wave packs its own 256 px of mask bits
// (in-wave LDS write->read needs no __syncthreads), runs 3 MFMAs per
// 32-px group (sum, sq, count-via-B=ones), and atomics its own C-frags
// into a per-wave workspace slice. No block-level sync anywhere.
__global__ __launch_bounds__(THREADS) void disc_mfma_kernel(
    const float* __restrict__ emb, const int* __restrict__ masks,
    float* __restrict__ ws)   // NSLICE slices of [cnt 64 | sum 1024 | sq 1024]
{
    __shared__ __align__(16) unsigned short bits[TPB];  // 2 KB, per-wave regions

    const int tid = threadIdx.x;
    const int lane = tid & 63;
    const int wave = tid >> 6;
    const int b = blockIdx.x / NTILES;
    const int tile = blockIdx.x % NTILES;
    const size_t tile0 = (size_t)tile * TPB;
    const int wbase = wave * TPW;   // this wave's pixel base within the tile
    float* slice = ws + (size_t)((blockIdx.x * 4 + wave) & (NSLICE - 1)) * WSTOT;

    const int quad = lane >> 4;     // 0..3
    const int r = lane & 15;        // A-row (mask idx) == B-col (channel idx)

    // ---- pack this wave's mask bits: 2 chunks x 128 px, 2 px/lane/chunk ----
    const int* mbase = masks + (size_t)b * KK * HWP + tile0 + wbase;
    #pragma unroll
    for (int c = 0; c < 2; ++c) {
        unsigned v0 = 0, v1 = 0;
        #pragma unroll
        for (int k = 0; k < KK; ++k) {
            int2 mm = *(const int2*)(mbase + (size_t)k * HWP + c * 128 + 2 * lane);
            v0 |= (mm.x > 0 ? 1u : 0u) << k;
            v1 |= (mm.y > 0 ? 1u : 0u) << k;
        }
        // pixels wbase+c*128+2*lane, +1  (consecutive uint per lane: conflict-free)
        ((unsigned*)bits)[(wbase + c * 128) / 2 + lane] = v0 | (v1 << 16);
    }
    // no barrier: each wave reads only what its own lanes wrote (DS ops are
    // wave-ordered; compiler inserts the lgkmcnt wait)

    // ---- MFMA over 8 groups of 32 px; 3 MFMAs per group ----
    union { bf16x8 v; unsigned short s[8]; } Bones;
    #pragma unroll
    for (int i = 0; i < 8; ++i) Bones.s[i] = 0x3F80;   // bf16 1.0

    const float* ebase = emb + ((size_t)b * CC + r) * HWP + tile0;  // channel r

    f32x4 acc_s = {0.f, 0.f, 0.f, 0.f};
    f32x4 acc_q = {0.f, 0.f, 0.f, 0.f};
    f32x4 acc_c = {0.f, 0.f, 0.f, 0.f};

    #pragma unroll
    for (int g = 0; g < TPW / 32; ++g) {
        const int p0 = wbase + g * 32;

        // A-frag: mask bit r of pixels p0+quad*8 .. +7 (16B broadcast LDS read)
        uint4 bw = *(const uint4*)&bits[p0 + quad * 8];
        union { bf16x8 v; unsigned u[4]; } A;
        A.u[0] = ((bw.x >> r) & 0x00010001u) * 0x3F80u;
        A.u[1] = ((bw.y >> r) & 0x00010001u) * 0x3F80u;
        A.u[2] = ((bw.z >> r) & 0x00010001u) * 0x3F80u;
        A.u[3] = ((bw.w >> r) & 0x00010001u) * 0x3F80u;

        // B-frags: channel r, pixels p0+quad*8 .. +7 (two float4 loads)
        const float4* ep = (const float4*)(ebase + p0 + quad * 8);
        float4 f0 = ep[0], f1 = ep[1];
        const float e[8] = {f0.x, f0.y, f0.z, f0.w, f1.x, f1.y, f1.z, f1.w};
        union { bf16x8 v; unsigned short s[8]; } Bf, B2;
        #pragma unroll
        for (int i = 0; i < 8; ++i) {
            Bf.s[i] = f2bf(e[i]);
            B2.s[i] = f2bf(e[i] * e[i]);
        }

        acc_s = __builtin_amdgcn_mfma_f32_16x16x32_bf16(A.v, Bf.v, acc_s, 0, 0, 0);
        acc_q = __builtin_amdgcn_mfma_f32_16x16x32_bf16(A.v, B2.v, acc_q, 0, 0, 0);
        acc_c = __builtin_amdgcn_mfma_f32_16x16x32_bf16(A.v, Bones.v, acc_c, 0, 0, 0);
    }

    // ---- per-wave atomic epilogue (C/D: col=lane&15, row=(lane>>4)*4+reg) ----
    #pragma unroll
    for (int reg = 0; reg < 4; ++reg) {
        const int krow = quad * 4 + reg;
        atomicAdd(&slice[64 + ((size_t)b * KK + krow) * CC + r], acc_s[reg]);
        atomicAdd(&slice[64 + 1024 + ((size_t)b * KK + krow) * CC + r], acc_q[reg]);
    }
    if (r == 0) {   // count cols are all identical; col 0 lanes own rows quad*4..+3
        #pragma unroll
        for (int reg = 0; reg < 4; ++reg) {
            atomicAdd(&slice[b * KK + quad * 4 + reg], acc_c[reg]);
        }
    }
}

__global__ __launch_bounds__(256) void disc_finalize_kernel(
    const float* __restrict__ ws, float* __restrict__ out)
{
    __shared__ float red[WSTOT];             // slice-reduced [cnt|sum|sq]
    __shared__ float means[BB][KK][CC];
    __shared__ float partial[BB];
    const int tid = threadIdx.x;

    for (int idx = tid; idx < WSTOT; idx += 256) {
        float t = 0.f;
        #pragma unroll
        for (int s = 0; s < NSLICE; ++s) t += ws[(size_t)s * WSTOT + idx];
        red[idx] = t;
    }
    __syncthreads();

    const float* red_cnt = red;
    const float* red_sum = red + 64;
    const float* red_sq  = red + 64 + 1024;

    const int b = tid >> 6;       // one wave per batch
    const int lane = tid & 63;

    const float DELTA_PULL = 0.5f;
    const float DELTA_PUSH = 1.5f;
    const float EPS = 1e-6f;

    float cntk = 0.f;
    bool valid = false;
    float pull_k = 0.f;
    if (lane < KK) {
        int k = lane;
        cntk = red_cnt[b * KK + k];
        valid = cntk > 0.f;
        float safe = fmaxf_(cntk, 1.f);
        float acc_sq = 0.f, acc_ss = 0.f;
        #pragma unroll
        for (int c = 0; c < CC; ++c) {
            float sv = red_sum[(b * KK + k) * CC + c];
            means[b][k][c] = sv / safe;
            acc_sq += red_sq[(b * KK + k) * CC + c];
            acc_ss += sv * sv;
        }
        if (valid) pull_k = (acc_sq - acc_ss / cntk) / (cntk + EPS);
    }

    unsigned long long bal = __ballot(lane < KK && valid);
    float M = (float)__popcll(bal);

    float ps = pull_k;
    #pragma unroll
    for (int d = 32; d >= 1; d >>= 1) ps += __shfl_xor(ps, d, 64);
    float pull_b = ps / fmaxf_(M, 1.f);

    __syncthreads();

    float push = 0.f;
    for (int t = lane; t < KK * KK; t += 64) {
        int i = t >> 4, j = t & 15;
        if (i < j && ((bal >> i) & 1ull) && ((bal >> j) & 1ull)) {
            float d2 = 1e-12f;
            #pragma unroll
            for (int c = 0; c < CC; ++c) {
                float df = means[b][i][c] - means[b][j][c];
                d2 = fmaf(df, df, d2);
            }
            float dist = sqrtf(d2);
            float h = fmaxf_(DELTA_PUSH - dist, 0.f);
            push += h * h;
        }
    }
    #pragma unroll
    for (int d = 32; d >= 1; d >>= 1) push += __shfl_xor(push, d, 64);

    if (lane == 0) {
        float npairs = M * (M - 1.f) * 0.5f;
        float push_b = (M > 1.f) ? push / fmaxf_(npairs, 1.f) : 0.f;
        partial[b] = DELTA_PULL * pull_b + push_b;
    }
    __syncthreads();
    if (tid == 0) {
        out[0] = (partial[0] + partial[1] + partial[2] + partial[3]) * 0.25f;
    }
}

extern "C" void kernel_launch(void* const* d_in, const int* in_sizes, int n_in,
                              void* d_out, int out_size, void* d_ws, size_t ws_size,
                              hipStream_t stream) {
    const float* emb = (const float*)d_in[0];
    const int* masks = (const int*)d_in[1];
    float* ws = (float*)d_ws;

    hipMemsetAsync(d_ws, 0, NSLICE * WSTOT * sizeof(float), stream);

    dim3 grid(BB * NTILES);
    disc_mfma_kernel<<<grid, THREADS, 0, stream>>>(emb, masks, ws);
    disc_finalize_kernel<<<1, 256, 0, stream>>>(ws, (float*)d_out);
}